// Round 6
// baseline (168.461 us; speedup 1.0000x reference)
//
#include <hip/hip_runtime.h>
#include <math.h>

// ---- geometry ----
// Grid 50^3, coords shifted +1 -> occupy [1,50]. Dense key = (z*GY+y)*64+x.
// 8-deep z bricks probe z up to 57 -> z-dim 58.
#define GY 54
#define ZD 58
#define NROWS (ZD*GY*64)      // 200448 keys

// brick 8x4x8 = 256 output voxels per block; halo 10x6x10 = 600 rows
#define HX 10
#define HY 6
#define HXY 60                // halo rows per z-slice
#define NH 600
#define NBX 7
#define NBY 13
#define NBZ 7
#define NBRICK (NBX*NBY*NBZ)  // 637

// split-K=2: each brick -> 2 blocks, each handling 2 cin-quarter passes.
#define NBLK (2*NBRICK)       // 1274
#define SLAB2 160             // ceil(1274/8); even -> split pairs share an XCD

#define K3CC (27*64*64)       // 110592 weight elements

typedef __bf16  bf16x8 __attribute__((ext_vector_type(8)));
typedef float  f32x16 __attribute__((ext_vector_type(16)));

// global->LDS DMA, 16B per lane, linear LDS dest (wave-uniform base + lane*16)
#define AS1 __attribute__((address_space(1)))
#define AS3 __attribute__((address_space(3)))
#define GLD_LDS16(g, l) \
    __builtin_amdgcn_global_load_lds((const AS1 void*)(g), (AS3 void*)(l), 16, 0, 0)

// ---- fused prep: maps + reverse keys + Wt4 + feats->bf16 + zero row + out=bias ----
__global__ void prep_kernel(const float* __restrict__ ipos, int n,
                            const float* __restrict__ opos, int m,
                            const float* __restrict__ vsp,
                            const float* __restrict__ W,
                            const float* __restrict__ feats,
                            const float* __restrict__ bias,
                            int* __restrict__ imap, int* __restrict__ ikey,
                            int* __restrict__ omap, int* __restrict__ okey,
                            __bf16* __restrict__ Wt4,
                            __bf16* __restrict__ zrow,
                            __bf16* __restrict__ featsB,
                            float* __restrict__ out) {
    int i = blockIdx.x * 256 + threadIdx.x;
    float vs = vsp[0];
    if (i < n) {
        int x = (int)floorf(ipos[3*i+0] / vs) + 1;
        int y = (int)floorf(ipos[3*i+1] / vs) + 1;
        int z = (int)floorf(ipos[3*i+2] / vs) + 1;
        int key = (z * GY + y) * 64 + x;
        ikey[i] = key;
        imap[key] = i;
    } else if (i < n + m) {
        int j = i - n;
        int x = (int)floorf(opos[3*j+0] / vs) + 1;
        int y = (int)floorf(opos[3*j+1] / vs) + 1;
        int z = (int)floorf(opos[3*j+2] / vs) + 1;
        int key = (z * GY + y) * 64 + x;
        okey[j] = key;
        omap[key] = j;
    } else if (i < n + m + K3CC) {
        int k  = i - n - m;
        int t  = k >> 12;
        int r  = k & 4095;
        int ci = r >> 6;
        int co = r & 63;
        int p   = ci >> 4;
        int cil = ci & 15;
        Wt4[(((p * 27 + t) << 6) + co) * 16 + cil] = (__bf16)W[k];
    } else if (i < n + m + K3CC + 32) {
        zrow[i - n - m - K3CC] = (__bf16)0.f;
    } else {
        int j = i - n - m - K3CC - 32;
        if (j < n * 8) {                       // one bf16x8 chunk of featsB
            const float4* s = (const float4*)(feats + (size_t)j * 8);
            float4 f0 = s[0], f1 = s[1];
            bf16x8 v;
            v[0]=(__bf16)f0.x; v[1]=(__bf16)f0.y; v[2]=(__bf16)f0.z; v[3]=(__bf16)f0.w;
            v[4]=(__bf16)f1.x; v[5]=(__bf16)f1.y; v[6]=(__bf16)f1.z; v[7]=(__bf16)f1.w;
            *(bf16x8*)(featsB + (size_t)j * 8) = v;
        } else {
            int j2 = j - n * 8;                // out = bias (16 floats per thread)
            if (j2 < m * 4) {
                const float4* b4 = (const float4*)bias;
                float4* o4 = (float4*)out + (size_t)j2 * 4;
                int c4 = (j2 & 3) * 4;
                o4[0] = b4[c4]; o4[1] = b4[c4+1]; o4[2] = b4[c4+2]; o4[3] = b4[c4+3];
            }
        }
    }
}

// tap body: macro (NOT lambda -- by-ref capture demoted acc to scratch, r1).
// Round-4 wave shape (proven best ratio): 2 A-LDS-reads + 2 B-global-reads
// + 4 MFMAs per tap. B wave-uniform per block -> L1-hot.
// SQ_LDS_BANK_CONFLICT tallies ~8/read = wave64 b128 LDS-pipe floor; ignore.
#define TAP_BODY(t)                                                            \
    {                                                                          \
        const int drow = ((t)/9 - 1)*HXY + (((t)/3)%3 - 1)*HX + ((t)%3 - 1);   \
        bf16x8 a0 = *(const bf16x8*)(Ab0 + drow * 16);                         \
        bf16x8 a1 = *(const bf16x8*)(Ab0 + (drow + HXY) * 16);                 \
        bf16x8 b0 = *(const bf16x8*)(Bg0 + (t) * 1024);                        \
        bf16x8 b1 = *(const bf16x8*)(Bg0 + (t) * 1024 + 512);                  \
        acc00 = __builtin_amdgcn_mfma_f32_32x32x16_bf16(a0, b0, acc00, 0, 0, 0); \
        acc01 = __builtin_amdgcn_mfma_f32_32x32x16_bf16(a0, b1, acc01, 0, 0, 0); \
        acc10 = __builtin_amdgcn_mfma_f32_32x32x16_bf16(a1, b0, acc10, 0, 0, 0); \
        acc11 = __builtin_amdgcn_mfma_f32_32x32x16_bf16(a1, b1, acc11, 0, 0, 0); \
    }

// (256,2): never squeeze the allocator (min-waves>=3 spilled the 64-reg acc
// twice). Single-buffer halo -> 22.6KB LDS -> 7 blocks/CU capacity; grid
// needs ~5 -> all 1274 blocks co-resident (~20 waves/CU).
__global__ __launch_bounds__(256, 2) void conv_kernel(
    const __bf16* __restrict__ featsB,  // [N,64] bf16
    const __bf16* __restrict__ Wt4,     // [4][27][64cout][16cin]
    const __bf16* __restrict__ zrow,    // 32 zero bf16
    const int*   __restrict__ imap,
    const int*   __restrict__ ikey,
    const int*   __restrict__ omap,
    const int*   __restrict__ okey,
    float*       __restrict__ out,      // [M,64], pre-init with bias
    int N, int M)
{
    __shared__ __align__(16) __bf16 halo[NH * 16];   // 19200 B (single buffer)
    __shared__ int ridx[NH];                         //  2400 B
    __shared__ int obuf[256];                        //  1024 B
    // total ~22.6 KB

    const int tid = threadIdx.x;

    // XCD slab swizzle; split pair (q=2k, 2k+1) stays on one XCD -> their
    // halo/B reads and out atomics share that XCD's L2.
    int q = (blockIdx.x & 7) * SLAB2 + (blockIdx.x >> 3);
    if (q >= NBLK) return;   // block-uniform exit before any barrier
    const int brick = q >> 1;
    const int s     = q & 1;           // this block's K-split: passes {2s, 2s+1}
    const int bx = brick % NBX;
    int rem = brick / NBX;
    const int by = rem % NBY;
    const int bz = rem / NBY;

    // ---- resolve halo row indices (validated) + output rows ----
    #pragma unroll
    for (int it = 0; it < 3; ++it) {
        int r = it * 256 + tid;
        if (r < NH) {
            int xs = r % HX;
            int t2 = r / HX;
            int ys = t2 % HY;
            int zs = t2 / HY;
            int key = ((bz*8 + zs) * GY + (by*4 + ys)) * 64 + (bx*8 + xs);
            int idx = imap[key];
            int c = min(max(idx, 0), N - 1);
            ridx[r] = (idx >= 0 && idx < N && ikey[c] == key) ? idx : -1;
        }
    }
    {
        int x = tid & 7, y = (tid >> 3) & 3, z = tid >> 5;
        int key = ((bz*8 + z + 1) * GY + (by*4 + y + 1)) * 64 + (bx*8 + x + 1);
        int o = omap[key];
        int c = min(max(o, 0), M - 1);
        obuf[tid] = (o >= 0 && o < M && okey[c] == key) ? o : -1;
    }

    // compute roles: wave owns z-slices {2w, 2w+1} (2 m-tiles) x both n-tiles
    const int wave  = tid >> 6;
    const int lane  = tid & 63;
    const int lrow  = lane & 31;
    const int halfk = lane >> 5;
    const int xv = lrow & 7, yv = (lrow >> 3) & 3;
    const int arow0 = (2*wave + 1) * HXY + (yv + 1) * HX + (xv + 1);

    f32x16 acc00, acc01, acc10, acc11;
    #pragma unroll
    for (int i = 0; i < 16; ++i) { acc00[i]=0.f; acc01[i]=0.f; acc10[i]=0.f; acc11[i]=0.f; }

    __syncthreads();   // ridx + obuf visible

    // ---- prologue: DMA halo quarter p=2s ----
    #pragma unroll
    for (int it = 0; it < 5; ++it) {
        int task = it * 256 + tid;
        if (task < NH * 2) {
            int r  = task >> 1;
            int hl = task & 1;
            int idx = ridx[r];
            const __bf16* src = (idx >= 0)
                ? featsB + (size_t)idx * 64 + 2*s*16 + hl * 8
                : zrow;
            GLD_LDS16(src, (char*)halo + task * 16);
        }
    }
    __syncthreads();   // vmcnt(0) drain -> halo ready

    #pragma unroll 1
    for (int pi = 0; pi < 2; ++pi) {
        const int p = 2*s + pi;
        if (pi) {
            __syncthreads();   // pass-0 readers done before overwrite
            #pragma unroll
            for (int it = 0; it < 5; ++it) {
                int task = it * 256 + tid;
                if (task < NH * 2) {
                    int r  = task >> 1;
                    int hl = task & 1;
                    int idx = ridx[r];
                    const __bf16* src = (idx >= 0)
                        ? featsB + (size_t)idx * 64 + p * 16 + hl * 8
                        : zrow;
                    GLD_LDS16(src, (char*)halo + task * 16);
                }
            }
            __syncthreads();   // refill visible; exposed latency hidden by
                               // ~5 co-resident blocks/CU
        }

        // ---- 27 taps: A from LDS, B from global (L1/L2-hot) ----
        const __bf16* Ab0 = halo + arow0 * 16 + halfk * 8;
        const __bf16* Bg0 = Wt4 + (size_t)p * 27648 + lrow * 16 + halfk * 8;

        #pragma unroll
        for (int t = 0; t < 27; ++t) TAP_BODY(t)
    }

    // ---- epilogue: atomic accumulate (out pre-init with bias; 2 splits/brick)
    // C/D layout col=lane&31, row=(reg&3)+8*(reg>>2)+4*(lane>>5)
    const int col0 = lrow, col1 = 32 + lrow;
    #pragma unroll
    for (int r = 0; r < 16; ++r) {
        int mrow = (r & 3) + 8 * (r >> 2) + 4 * halfk;
        int o0 = obuf[(2*wave)     * 32 + mrow];
        int o1 = obuf[(2*wave + 1) * 32 + mrow];
        if (o0 >= 0) {
            atomicAdd(out + (size_t)o0 * 64 + col0, acc00[r]);
            atomicAdd(out + (size_t)o0 * 64 + col1, acc01[r]);
        }
        if (o1 >= 0) {
            atomicAdd(out + (size_t)o1 * 64 + col0, acc10[r]);
            atomicAdd(out + (size_t)o1 * 64 + col1, acc11[r]);
        }
    }
}

extern "C" void kernel_launch(void* const* d_in, const int* in_sizes, int n_in,
                              void* d_out, int out_size, void* d_ws, size_t ws_size,
                              hipStream_t stream) {
    const float* feats = (const float*)d_in[0];
    const float* ipos  = (const float*)d_in[1];
    const float* opos  = (const float*)d_in[2];
    const float* vsp   = (const float*)d_in[3];
    const float* W     = (const float*)d_in[4];
    const float* bias  = (const float*)d_in[5];

    int N = in_sizes[0] / 64;
    int M = out_size / 64;

    // workspace: imap | omap | ikey | okey | Wt4 | zrow | featsB (~15.5 MB)
    int*    imap   = (int*)d_ws;
    int*    omap   = imap + NROWS;
    int*    ikey   = omap + NROWS;
    int*    okey   = ikey + N;
    __bf16* Wt4    = (__bf16*)(okey + M);
    __bf16* zrow   = Wt4 + K3CC;
    __bf16* featsB = zrow + 32;

    int total = N + M + K3CC + 32 + N * 8 + M * 4;
    prep_kernel<<<(total + 255) / 256, 256, 0, stream>>>(ipos, N, opos, M, vsp, W, feats,
                                                         bias, imap, ikey, omap, okey,
                                                         Wt4, zrow, featsB, (float*)d_out);
    conv_kernel<<<8 * SLAB2, 256, 0, stream>>>(featsB, Wt4, zrow,
                                               imap, ikey, omap, okey,
                                               (float*)d_out, N, M);
}

// Round 7
// 161.169 us; speedup vs baseline: 1.0453x; 1.0453x over previous
//
#include <hip/hip_runtime.h>
#include <math.h>

// ---- geometry ----
// Grid 50^3, coords shifted +1 -> occupy [1,50]. Dense key = (z*GY+y)*64+x.
// 8-deep z bricks probe z up to 57 -> z-dim 58.
#define GY 54
#define ZD 58
#define NROWS (ZD*GY*64)      // 200448 keys

// brick 8x4x8 = 256 output voxels per block; halo 10x6x10 = 600 rows
#define HX 10
#define HY 6
#define HXY 60                // halo rows per z-slice
#define NH 600
#define NBX 7
#define NBY 13
#define NBZ 7
#define NBRICK (NBX*NBY*NBZ)  // 637
#define SLAB 80               // ceil(637/8)

#define K3CC (27*64*64)       // 110592 weight elements

typedef __bf16  bf16x8 __attribute__((ext_vector_type(8)));
typedef float  f32x16 __attribute__((ext_vector_type(16)));

// global->LDS DMA, 16B per lane, linear LDS dest (wave-uniform base + lane*16)
#define AS1 __attribute__((address_space(1)))
#define AS3 __attribute__((address_space(3)))
#define GLD_LDS16(g, l) \
    __builtin_amdgcn_global_load_lds((const AS1 void*)(g), (AS3 void*)(l), 16, 0, 0)

// ---- fused prep: maps + reverse keys + Wt4 + feats->bf16 + zero row ----
__global__ void prep_kernel(const float* __restrict__ ipos, int n,
                            const float* __restrict__ opos, int m,
                            const float* __restrict__ vsp,
                            const float* __restrict__ W,
                            const float* __restrict__ feats,
                            int* __restrict__ imap, int* __restrict__ ikey,
                            int* __restrict__ omap, int* __restrict__ okey,
                            __bf16* __restrict__ Wt4,
                            __bf16* __restrict__ zrow,
                            __bf16* __restrict__ featsB) {
    int i = blockIdx.x * 256 + threadIdx.x;
    float vs = vsp[0];
    if (i < n) {
        int x = (int)floorf(ipos[3*i+0] / vs) + 1;
        int y = (int)floorf(ipos[3*i+1] / vs) + 1;
        int z = (int)floorf(ipos[3*i+2] / vs) + 1;
        int key = (z * GY + y) * 64 + x;
        ikey[i] = key;
        imap[key] = i;
    } else if (i < n + m) {
        int j = i - n;
        int x = (int)floorf(opos[3*j+0] / vs) + 1;
        int y = (int)floorf(opos[3*j+1] / vs) + 1;
        int z = (int)floorf(opos[3*j+2] / vs) + 1;
        int key = (z * GY + y) * 64 + x;
        okey[j] = key;
        omap[key] = j;
    } else if (i < n + m + K3CC) {
        int k  = i - n - m;
        int t  = k >> 12;
        int r  = k & 4095;
        int ci = r >> 6;
        int co = r & 63;
        int p   = ci >> 4;
        int cil = ci & 15;
        Wt4[(((p * 27 + t) << 6) + co) * 16 + cil] = (__bf16)W[k];
    } else if (i < n + m + K3CC + 32) {
        zrow[i - n - m - K3CC] = (__bf16)0.f;
    } else {
        int j = i - n - m - K3CC - 32;         // one bf16x8 chunk of featsB
        if (j < n * 8) {
            const float4* s = (const float4*)(feats + (size_t)j * 8);
            float4 f0 = s[0], f1 = s[1];
            bf16x8 v;
            v[0]=(__bf16)f0.x; v[1]=(__bf16)f0.y; v[2]=(__bf16)f0.z; v[3]=(__bf16)f0.w;
            v[4]=(__bf16)f1.x; v[5]=(__bf16)f1.y; v[6]=(__bf16)f1.z; v[7]=(__bf16)f1.w;
            *(bf16x8*)(featsB + (size_t)j * 8) = v;
        }
    }
}

// Fused-K structure: full 64-cin halo staged ONCE (one DMA burst, one
// barrier), then a single barrier-free stretch of 27 taps x 16 MFMA.
// Per tap: 8 A ds_reads + 8 wave-uniform B global loads (L1-hot) + 16 MFMA.
// Accs chain 4-deep per tap (4 passes) but 4 independent accs interleave:
// 128 issue cycles >= 72-cycle chain -> no dependency bubble.
// SQ_LDS_BANK_CONFLICT tallies ~8/b128-read = wave64 LDS-pipe floor; ignore.
//
// (256,2): min-waves>=3 spilled the 64-reg acc twice -- never cap tighter.
__global__ __launch_bounds__(256, 2) void conv_kernel(
    const __bf16* __restrict__ featsB,  // [N,64] bf16
    const __bf16* __restrict__ Wt4,     // [4][27][64cout][16cin]
    const __bf16* __restrict__ zrow,    // 32 zero bf16
    const float* __restrict__ bias,     // [64]
    const int*   __restrict__ imap,
    const int*   __restrict__ ikey,
    const int*   __restrict__ omap,
    const int*   __restrict__ okey,
    float*       __restrict__ out,      // [M,64]
    int N, int M)
{
    __shared__ __align__(16) __bf16 halo[NH * 64];   // 76800 B: full 64-cin rows
    __shared__ int ridx[NH];                         //  2400 B
    __shared__ int obuf[256];                        //  1024 B
    // total 80224 B -> rounds to ~80.4 KB -> 2 blocks/CU (160.8 <= 160 KiB=163840 B)

    const int tid = threadIdx.x;

    // XCD slab swizzle
    int q = (blockIdx.x & 7) * SLAB + (blockIdx.x >> 3);
    if (q >= NBRICK) return;   // block-uniform exit before any barrier
    const int bx = q % NBX;
    int rem = q / NBX;
    const int by = rem % NBY;
    const int bz = rem / NBY;

    // ---- resolve halo row indices (validated) + output rows ----
    #pragma unroll
    for (int it = 0; it < 3; ++it) {
        int r = it * 256 + tid;
        if (r < NH) {
            int xs = r % HX;
            int t2 = r / HX;
            int ys = t2 % HY;
            int zs = t2 / HY;
            int key = ((bz*8 + zs) * GY + (by*4 + ys)) * 64 + (bx*8 + xs);
            int idx = imap[key];
            int c = min(max(idx, 0), N - 1);
            ridx[r] = (idx >= 0 && idx < N && ikey[c] == key) ? idx : -1;
        }
    }
    {
        int x = tid & 7, y = (tid >> 3) & 3, z = tid >> 5;
        int key = ((bz*8 + z + 1) * GY + (by*4 + y + 1)) * 64 + (bx*8 + x + 1);
        int o = omap[key];
        int c = min(max(o, 0), M - 1);
        obuf[tid] = (o >= 0 && o < M && okey[c] == key) ? o : -1;
    }

    // compute roles: wave owns z-slices {2w, 2w+1} (2 m-tiles) x both n-tiles
    const int wave  = tid >> 6;
    const int lane  = tid & 63;
    const int lrow  = lane & 31;
    const int halfk = lane >> 5;
    const int xv = lrow & 7, yv = (lrow >> 3) & 3;
    const int arow0 = (2*wave + 1) * HXY + (yv + 1) * HX + (xv + 1);

    f32x16 acc00, acc01, acc10, acc11;
    #pragma unroll
    for (int i = 0; i < 16; ++i) { acc00[i]=0.f; acc01[i]=0.f; acc10[i]=0.f; acc11[i]=0.f; }

    __syncthreads();   // ridx + obuf visible

    // ---- single DMA burst: 600 rows x 128 B (all 64 cin) ----
    // task = row*8 + chunk; LDS byte task*16 == row*128 + chunk*16, which the
    // tap loop reads as element row*64 + p*16 + halfk*8 (chunk = 2p+halfk).
    #pragma unroll
    for (int it = 0; it < 19; ++it) {
        int task = it * 256 + tid;
        if (task < NH * 8) {
            int r = task >> 3;
            int c = task & 7;
            int idx = ridx[r];
            const __bf16* src = (idx >= 0) ? featsB + (size_t)idx * 64 + c * 8
                                           : zrow;
            GLD_LDS16(src, (char*)halo + task * 16);
        }
    }
    __syncthreads();   // vmcnt(0) drain -> whole halo ready; LAST barrier

    // ---- 27 taps x 4 cin-quarters, zero barriers ----
    const __bf16* Ab  = halo + arow0 * 64 + halfk * 8;
    const __bf16* Bg0 = Wt4 + lrow * 16 + halfk * 8;

    #pragma unroll 1
    for (int dz = 0; dz < 3; ++dz) {
        const __bf16* Az = Ab + (dz - 1) * (HXY * 64);
        const __bf16* Bz = Bg0 + dz * 9 * 1024;
        #pragma unroll
        for (int tq = 0; tq < 9; ++tq) {
            const int drow = (tq / 3 - 1) * HX + (tq % 3 - 1);
            #pragma unroll
            for (int p = 0; p < 4; ++p) {
                bf16x8 a0 = *(const bf16x8*)(Az + drow * 64 + p * 16);
                bf16x8 a1 = *(const bf16x8*)(Az + (drow + HXY) * 64 + p * 16);
                bf16x8 b0 = *(const bf16x8*)(Bz + tq * 1024 + p * 27648);
                bf16x8 b1 = *(const bf16x8*)(Bz + tq * 1024 + p * 27648 + 512);
                acc00 = __builtin_amdgcn_mfma_f32_32x32x16_bf16(a0, b0, acc00, 0, 0, 0);
                acc01 = __builtin_amdgcn_mfma_f32_32x32x16_bf16(a0, b1, acc01, 0, 0, 0);
                acc10 = __builtin_amdgcn_mfma_f32_32x32x16_bf16(a1, b0, acc10, 0, 0, 0);
                acc11 = __builtin_amdgcn_mfma_f32_32x32x16_bf16(a1, b1, acc11, 0, 0, 0);
            }
        }
    }

    // ---- epilogue: C/D layout col=lane&31, row=(reg&3)+8*(reg>>2)+4*(lane>>5) ----
    const int col0 = lrow, col1 = 32 + lrow;
    const float bv0 = bias[col0], bv1 = bias[col1];
    #pragma unroll
    for (int r = 0; r < 16; ++r) {
        int mrow = (r & 3) + 8 * (r >> 2) + 4 * halfk;
        int o0 = obuf[(2*wave)     * 32 + mrow];
        int o1 = obuf[(2*wave + 1) * 32 + mrow];
        if (o0 >= 0) {
            out[(size_t)o0 * 64 + col0] = acc00[r] + bv0;
            out[(size_t)o0 * 64 + col1] = acc01[r] + bv1;
        }
        if (o1 >= 0) {
            out[(size_t)o1 * 64 + col0] = acc10[r] + bv0;
            out[(size_t)o1 * 64 + col1] = acc11[r] + bv1;
        }
    }
}

extern "C" void kernel_launch(void* const* d_in, const int* in_sizes, int n_in,
                              void* d_out, int out_size, void* d_ws, size_t ws_size,
                              hipStream_t stream) {
    const float* feats = (const float*)d_in[0];
    const float* ipos  = (const float*)d_in[1];
    const float* opos  = (const float*)d_in[2];
    const float* vsp   = (const float*)d_in[3];
    const float* W     = (const float*)d_in[4];
    const float* bias  = (const float*)d_in[5];

    int N = in_sizes[0] / 64;
    int M = out_size / 64;

    // workspace: imap | omap | ikey | okey | Wt4 | zrow | featsB (~15.5 MB)
    int*    imap   = (int*)d_ws;
    int*    omap   = imap + NROWS;
    int*    ikey   = omap + NROWS;
    int*    okey   = ikey + N;
    __bf16* Wt4    = (__bf16*)(okey + M);
    __bf16* zrow   = Wt4 + K3CC;
    __bf16* featsB = zrow + 32;

    int total = N + M + K3CC + 32 + N * 8;
    prep_kernel<<<(total + 255) / 256, 256, 0, stream>>>(ipos, N, opos, M, vsp, W, feats,
                                                         imap, ikey, omap, okey,
                                                         Wt4, zrow, featsB);
    conv_kernel<<<8 * SLAB, 256, 0, stream>>>(featsB, Wt4, zrow, bias,
                                              imap, ikey, omap, okey,
                                              (float*)d_out, N, M);
}

// Round 9
// 156.833 us; speedup vs baseline: 1.0741x; 1.0276x over previous
//
#include <hip/hip_runtime.h>
#include <math.h>

// ---- geometry ----
// Grid 50^3, coords shifted +1 -> occupy [1,50]. Dense key = (z*GY+y)*64+x.
// 8-deep z bricks probe z up to 57 -> z-dim 58.
#define GY 54
#define ZD 58
#define NROWS (ZD*GY*64)      // 200448 keys

// brick 8x4x8 = 256 output voxels per block; halo 10x6x10 = 600 rows
#define HX 10
#define HY 6
#define HXY 60                // halo rows per z-slice
#define NH 600
#define NBX 7
#define NBY 13
#define NBZ 7
#define NBRICK (NBX*NBY*NBZ)  // 637
#define SLAB 80               // ceil(637/8)

#define K3CC (27*64*64)       // 110592 weight elements

typedef __bf16  bf16x8 __attribute__((ext_vector_type(8)));
typedef float  f32x16 __attribute__((ext_vector_type(16)));

// global->LDS DMA, 16B per lane, linear LDS dest (wave-uniform base + lane*16)
#define AS1 __attribute__((address_space(1)))
#define AS3 __attribute__((address_space(3)))
#define GLD_LDS16(g, l) \
    __builtin_amdgcn_global_load_lds((const AS1 void*)(g), (AS3 void*)(l), 16, 0, 0)

// ---- fused prep: maps + reverse keys + Wt4 + feats->bf16 + zero row ----
__global__ void prep_kernel(const float* __restrict__ ipos, int n,
                            const float* __restrict__ opos, int m,
                            const float* __restrict__ vsp,
                            const float* __restrict__ W,
                            const float* __restrict__ feats,
                            int* __restrict__ imap, int* __restrict__ ikey,
                            int* __restrict__ omap, int* __restrict__ okey,
                            __bf16* __restrict__ Wt4,
                            __bf16* __restrict__ zrow,
                            __bf16* __restrict__ featsB) {
    int i = blockIdx.x * 256 + threadIdx.x;
    float vs = vsp[0];
    if (i < n) {
        int x = (int)floorf(ipos[3*i+0] / vs) + 1;
        int y = (int)floorf(ipos[3*i+1] / vs) + 1;
        int z = (int)floorf(ipos[3*i+2] / vs) + 1;
        int key = (z * GY + y) * 64 + x;
        ikey[i] = key;
        imap[key] = i;
    } else if (i < n + m) {
        int j = i - n;
        int x = (int)floorf(opos[3*j+0] / vs) + 1;
        int y = (int)floorf(opos[3*j+1] / vs) + 1;
        int z = (int)floorf(opos[3*j+2] / vs) + 1;
        int key = (z * GY + y) * 64 + x;
        okey[j] = key;
        omap[key] = j;
    } else if (i < n + m + K3CC) {
        int k  = i - n - m;
        int t  = k >> 12;
        int r  = k & 4095;
        int ci = r >> 6;
        int co = r & 63;
        int p   = ci >> 4;
        int cil = ci & 15;
        Wt4[(((p * 27 + t) << 6) + co) * 16 + cil] = (__bf16)W[k];
    } else if (i < n + m + K3CC + 32) {
        zrow[i - n - m - K3CC] = (__bf16)0.f;
    } else {
        int j = i - n - m - K3CC - 32;         // one bf16x8 chunk of featsB
        if (j < n * 8) {
            const float4* s = (const float4*)(feats + (size_t)j * 8);
            float4 f0 = s[0], f1 = s[1];
            bf16x8 v;
            v[0]=(__bf16)f0.x; v[1]=(__bf16)f0.y; v[2]=(__bf16)f0.z; v[3]=(__bf16)f0.w;
            v[4]=(__bf16)f1.x; v[5]=(__bf16)f1.y; v[6]=(__bf16)f1.z; v[7]=(__bf16)f1.w;
            *(bf16x8*)(featsB + (size_t)j * 8) = v;
        }
    }
}

// Fused-K + XOR-swizzled halo.
// Bank-conflict model (closed by r4/r7 counters, EXACT): extra cycles per
// wave64 ds_read_b128 = f(row stride). 32B stride: 8 (floor). 128B stride
// unswizzled: 28 (32-way, all rows same bank slot -- r7's regression).
// Fix (rule #21): physical granule c of row r holds logical chunk c^(r&7);
// swizzle applied on DMA *source* (LDS dest linear), mirrored on read.
// r8 BUG, fixed here: row residue must be computed by PURE addition on
// (arow0&7) and XORed with halfk only at the END. XOR-then-add mixes
// carries and read wrong granules for halfk=1 lanes (absmax 9.08).
//
// (256,2): min-waves>=3 spilled the 64-reg acc twice -- never cap tighter.
__global__ __launch_bounds__(256, 2) void conv_kernel(
    const __bf16* __restrict__ featsB,  // [N,64] bf16
    const __bf16* __restrict__ Wt4,     // [4][27][64cout][16cin]
    const __bf16* __restrict__ zrow,    // 32 zero bf16
    const float* __restrict__ bias,     // [64]
    const int*   __restrict__ imap,
    const int*   __restrict__ ikey,
    const int*   __restrict__ omap,
    const int*   __restrict__ okey,
    float*       __restrict__ out,      // [M,64]
    int N, int M)
{
    __shared__ __align__(16) __bf16 halo[NH * 64];   // 76800 B: full 64-cin rows
    __shared__ int ridx[NH];                         //  2400 B
    __shared__ int obuf[256];                        //  1024 B
    // total ~80.4 KB -> 2 blocks/CU

    const int tid = threadIdx.x;

    // XCD slab swizzle
    int q = (blockIdx.x & 7) * SLAB + (blockIdx.x >> 3);
    if (q >= NBRICK) return;   // block-uniform exit before any barrier
    const int bx = q % NBX;
    int rem = q / NBX;
    const int by = rem % NBY;
    const int bz = rem / NBY;

    // ---- resolve halo row indices (validated) + output rows ----
    #pragma unroll
    for (int it = 0; it < 3; ++it) {
        int r = it * 256 + tid;
        if (r < NH) {
            int xs = r % HX;
            int t2 = r / HX;
            int ys = t2 % HY;
            int zs = t2 / HY;
            int key = ((bz*8 + zs) * GY + (by*4 + ys)) * 64 + (bx*8 + xs);
            int idx = imap[key];
            int c = min(max(idx, 0), N - 1);
            ridx[r] = (idx >= 0 && idx < N && ikey[c] == key) ? idx : -1;
        }
    }
    {
        int x = tid & 7, y = (tid >> 3) & 3, z = tid >> 5;
        int key = ((bz*8 + z + 1) * GY + (by*4 + y + 1)) * 64 + (bx*8 + x + 1);
        int o = omap[key];
        int c = min(max(o, 0), M - 1);
        obuf[tid] = (o >= 0 && o < M && okey[c] == key) ? o : -1;
    }

    // compute roles: wave owns z-slices {2w, 2w+1} (2 m-tiles) x both n-tiles
    const int wave  = tid >> 6;
    const int lane  = tid & 63;
    const int lrow  = lane & 31;
    const int halfk = lane >> 5;
    const int xv = lrow & 7, yv = (lrow >> 3) & 3;
    const int arow0 = (2*wave + 1) * HXY + (yv + 1) * HX + (xv + 1);

    f32x16 acc00, acc01, acc10, acc11;
    #pragma unroll
    for (int i = 0; i < 16; ++i) { acc00[i]=0.f; acc01[i]=0.f; acc10[i]=0.f; acc11[i]=0.f; }

    __syncthreads();   // ridx + obuf visible

    // ---- single DMA burst: 600 rows x 128 B (all 64 cin), source-swizzled ----
    // physical granule c of row r  <-  logical chunk c ^ (r&7).
    // Each row's 8 lanes read a permutation of the same 128 B span -> same
    // coalescing; LDS dest stays linear (DMA requirement).
    #pragma unroll
    for (int it = 0; it < 19; ++it) {
        int task = it * 256 + tid;
        if (task < NH * 8) {
            int r  = task >> 3;
            int cp = task & 7;
            int cl = cp ^ (r & 7);
            int idx = ridx[r];
            const __bf16* src = (idx >= 0) ? featsB + (size_t)idx * 64 + cl * 8
                                           : zrow;
            GLD_LDS16(src, (char*)halo + task * 16);
        }
    }
    __syncthreads();   // vmcnt(0) drain -> whole halo ready; LAST barrier

    // ---- 27 taps x 4 cin-quarters, zero barriers, swizzled A-reads ----
    // logical chunk (2p|halfk) of row r lives at granule (2p|halfk)^(r&7):
    // byte = r*128 + ((p<<5) ^ ((r7 ^ halfk)<<4)), r7 = TRUE row residue.
    // r7 arithmetic stays pure-additive on (arow0&7); halfk XORed at the end.
    // row+HXY: +60 mod 8 == XOR 4 -> u1 = u0 ^ 64.
    const int abase = arow0 * 128;
    const int r7b   = arow0 & 7;        // pure row residue (NO halfk here)
    const int hk4   = halfk << 4;
    const char* hb  = (const char*)halo;
    const __bf16* Bg0 = Wt4 + lrow * 16 + halfk * 8;

    #pragma unroll 1
    for (int dz = 0; dz < 3; ++dz) {
        const int zb = abase + (dz - 1) * (HXY * 128);
        const int z7 = (r7b + (dz - 1) * HXY) & 7;   // pure row residue
        const __bf16* Bz = Bg0 + dz * 9 * 1024;
        #pragma unroll
        for (int tq = 0; tq < 9; ++tq) {
            const int dr = (tq / 3 - 1) * HX + (tq % 3 - 1);
            const int b0 = zb + dr * 128;
            const int u0 = (((z7 + dr) & 7) << 4) ^ hk4;   // residue first, halfk last
            const int b1 = b0 + HXY * 128;
            const int u1 = u0 ^ 64;
            #pragma unroll
            for (int p = 0; p < 4; ++p) {
                bf16x8 a0 = *(const bf16x8*)(hb + b0 + ((p << 5) ^ u0));
                bf16x8 a1 = *(const bf16x8*)(hb + b1 + ((p << 5) ^ u1));
                bf16x8 bv0 = *(const bf16x8*)(Bz + tq * 1024 + p * 27648);
                bf16x8 bv1 = *(const bf16x8*)(Bz + tq * 1024 + p * 27648 + 512);
                acc00 = __builtin_amdgcn_mfma_f32_32x32x16_bf16(a0, bv0, acc00, 0, 0, 0);
                acc01 = __builtin_amdgcn_mfma_f32_32x32x16_bf16(a0, bv1, acc01, 0, 0, 0);
                acc10 = __builtin_amdgcn_mfma_f32_32x32x16_bf16(a1, bv0, acc10, 0, 0, 0);
                acc11 = __builtin_amdgcn_mfma_f32_32x32x16_bf16(a1, bv1, acc11, 0, 0, 0);
            }
        }
    }

    // ---- epilogue: C/D layout col=lane&31, row=(reg&3)+8*(reg>>2)+4*(lane>>5) ----
    const int col0 = lrow, col1 = 32 + lrow;
    const float bv0 = bias[col0], bv1 = bias[col1];
    #pragma unroll
    for (int r = 0; r < 16; ++r) {
        int mrow = (r & 3) + 8 * (r >> 2) + 4 * halfk;
        int o0 = obuf[(2*wave)     * 32 + mrow];
        int o1 = obuf[(2*wave + 1) * 32 + mrow];
        if (o0 >= 0) {
            out[(size_t)o0 * 64 + col0] = acc00[r] + bv0;
            out[(size_t)o0 * 64 + col1] = acc01[r] + bv1;
        }
        if (o1 >= 0) {
            out[(size_t)o1 * 64 + col0] = acc10[r] + bv0;
            out[(size_t)o1 * 64 + col1] = acc11[r] + bv1;
        }
    }
}

extern "C" void kernel_launch(void* const* d_in, const int* in_sizes, int n_in,
                              void* d_out, int out_size, void* d_ws, size_t ws_size,
                              hipStream_t stream) {
    const float* feats = (const float*)d_in[0];
    const float* ipos  = (const float*)d_in[1];
    const float* opos  = (const float*)d_in[2];
    const float* vsp   = (const float*)d_in[3];
    const float* W     = (const float*)d_in[4];
    const float* bias  = (const float*)d_in[5];

    int N = in_sizes[0] / 64;
    int M = out_size / 64;

    // workspace: imap | omap | ikey | okey | Wt4 | zrow | featsB (~15.5 MB)
    int*    imap   = (int*)d_ws;
    int*    omap   = imap + NROWS;
    int*    ikey   = omap + NROWS;
    int*    okey   = ikey + N;
    __bf16* Wt4    = (__bf16*)(okey + M);
    __bf16* zrow   = Wt4 + K3CC;
    __bf16* featsB = zrow + 32;

    int total = N + M + K3CC + 32 + N * 8;
    prep_kernel<<<(total + 255) / 256, 256, 0, stream>>>(ipos, N, opos, M, vsp, W, feats,
                                                         imap, ikey, omap, okey,
                                                         Wt4, zrow, featsB);
    conv_kernel<<<8 * SLAB, 256, 0, stream>>>(featsB, Wt4, zrow, bias,
                                              imap, ikey, omap, okey,
                                              (float*)d_out, N, M);
}

// Round 10
// 135.981 us; speedup vs baseline: 1.2389x; 1.1533x over previous
//
#include <hip/hip_runtime.h>
#include <math.h>

// ---- geometry ----
// Grid 50^3, coords shifted +1 -> occupy [1,50]. Dense key = (z*GY+y)*64+x.
// 8-deep z bricks probe z up to 57 -> z-dim 58.
#define GY 54
#define ZD 58
#define NROWS (ZD*GY*64)      // 200448 keys

// brick 8x4x8 = 256 output voxels per block; halo 10x6x10 = 600 rows
#define HX 10
#define HY 6
#define HXY 60                // halo rows per z-slice
#define NH 600
#define NBX 7
#define NBY 13
#define NBZ 7
#define NBRICK (NBX*NBY*NBZ)  // 637
#define SLAB 80               // ceil(637/8)

#define K3CC (27*64*64)       // 110592 weight elements

typedef __bf16  bf16x8 __attribute__((ext_vector_type(8)));
typedef float  f32x16 __attribute__((ext_vector_type(16)));

// global->LDS DMA, 16B per lane, linear LDS dest (wave-uniform base + lane*16)
#define AS1 __attribute__((address_space(1)))
#define AS3 __attribute__((address_space(3)))
#define GLD_LDS16(g, l) \
    __builtin_amdgcn_global_load_lds((const AS1 void*)(g), (AS3 void*)(l), 16, 0, 0)

// ---- fused prep: maps + reverse keys + Wt4 + feats->bf16 + zero row ----
__global__ void prep_kernel(const float* __restrict__ ipos, int n,
                            const float* __restrict__ opos, int m,
                            const float* __restrict__ vsp,
                            const float* __restrict__ W,
                            const float* __restrict__ feats,
                            int* __restrict__ imap, int* __restrict__ ikey,
                            int* __restrict__ omap, int* __restrict__ okey,
                            __bf16* __restrict__ Wt4,
                            __bf16* __restrict__ zrow,
                            __bf16* __restrict__ featsB) {
    int i = blockIdx.x * 256 + threadIdx.x;
    float vs = vsp[0];
    if (i < n) {
        int x = (int)floorf(ipos[3*i+0] / vs) + 1;
        int y = (int)floorf(ipos[3*i+1] / vs) + 1;
        int z = (int)floorf(ipos[3*i+2] / vs) + 1;
        int key = (z * GY + y) * 64 + x;
        ikey[i] = key;
        imap[key] = i;
    } else if (i < n + m) {
        int j = i - n;
        int x = (int)floorf(opos[3*j+0] / vs) + 1;
        int y = (int)floorf(opos[3*j+1] / vs) + 1;
        int z = (int)floorf(opos[3*j+2] / vs) + 1;
        int key = (z * GY + y) * 64 + x;
        okey[j] = key;
        omap[key] = j;
    } else if (i < n + m + K3CC) {
        int k  = i - n - m;
        int t  = k >> 12;
        int r  = k & 4095;
        int ci = r >> 6;
        int co = r & 63;
        int p   = ci >> 4;
        int cil = ci & 15;
        Wt4[(((p * 27 + t) << 6) + co) * 16 + cil] = (__bf16)W[k];
    } else if (i < n + m + K3CC + 32) {
        zrow[i - n - m - K3CC] = (__bf16)0.f;
    } else {
        int j = i - n - m - K3CC - 32;         // one bf16x8 chunk of featsB
        if (j < n * 8) {
            const float4* s = (const float4*)(feats + (size_t)j * 8);
            float4 f0 = s[0], f1 = s[1];
            bf16x8 v;
            v[0]=(__bf16)f0.x; v[1]=(__bf16)f0.y; v[2]=(__bf16)f0.z; v[3]=(__bf16)f0.w;
            v[4]=(__bf16)f1.x; v[5]=(__bf16)f1.y; v[6]=(__bf16)f1.z; v[7]=(__bf16)f1.w;
            *(bf16x8*)(featsB + (size_t)j * 8) = v;
        }
    }
}

// r4 structure (best measured: conv 53.5us) + explicit 4-deep B register
// ring. Theory: block lifetime (~35us, invariant r4/r9) is the per-tap
// exposed B-load L2 latency (~250cy) -- at VGPR=76 the compiler had no
// register room to pipeline. 4-tap lookahead (4 taps x ~56cy issue = 224cy)
// covers it. Ring slots indexed t&3 under FULL unroll -> static indices,
// stays in registers (rule #20). Ring prologue issued BEFORE the next-pass
// DMA so tap 0-3's vmcnt waits (FIFO order) don't force DMA completion.
// Halo: 32B-stride rows -> conflict counter at its 8-cyc wave64-b128 floor.
// (256,2): min-waves>=3 spilled the 64-reg acc twice -- never cap tighter.
__global__ __launch_bounds__(256, 2) void conv_kernel(
    const __bf16* __restrict__ featsB,  // [N,64] bf16
    const __bf16* __restrict__ Wt4,     // [4][27][64cout][16cin]
    const __bf16* __restrict__ zrow,    // 32 zero bf16
    const float* __restrict__ bias,     // [64]
    const int*   __restrict__ imap,
    const int*   __restrict__ ikey,
    const int*   __restrict__ omap,
    const int*   __restrict__ okey,
    float*       __restrict__ out,      // [M,64]
    int N, int M)
{
    __shared__ __align__(16) __bf16 halo[2 * NH * 16];        // 38400 B (double-buffered)
    __shared__ int ridx[NH];                                  //  2400 B
    __shared__ int obuf[256];                                 //  1024 B
    // total ~41.8 KB -> 3 blocks/CU (entire 637-block grid co-resident)

    const int tid = threadIdx.x;

    // XCD slab swizzle
    int q = (blockIdx.x & 7) * SLAB + (blockIdx.x >> 3);
    if (q >= NBRICK) return;   // block-uniform exit before any barrier
    const int bx = q % NBX;
    int rem = q / NBX;
    const int by = rem % NBY;
    const int bz = rem / NBY;

    // ---- resolve halo row indices (validated) + output rows ----
    #pragma unroll
    for (int it = 0; it < 3; ++it) {
        int r = it * 256 + tid;
        if (r < NH) {
            int xs = r % HX;
            int t2 = r / HX;
            int ys = t2 % HY;
            int zs = t2 / HY;
            int key = ((bz*8 + zs) * GY + (by*4 + ys)) * 64 + (bx*8 + xs);
            int idx = imap[key];
            int c = min(max(idx, 0), N - 1);
            ridx[r] = (idx >= 0 && idx < N && ikey[c] == key) ? idx : -1;
        }
    }
    {
        int x = tid & 7, y = (tid >> 3) & 3, z = tid >> 5;
        int key = ((bz*8 + z + 1) * GY + (by*4 + y + 1)) * 64 + (bx*8 + x + 1);
        int o = omap[key];
        int c = min(max(o, 0), M - 1);
        obuf[tid] = (o >= 0 && o < M && okey[c] == key) ? o : -1;
    }

    // compute roles: wave owns z-slices {2w, 2w+1} (2 m-tiles) x both n-tiles
    const int wave  = tid >> 6;
    const int lane  = tid & 63;
    const int lrow  = lane & 31;
    const int halfk = lane >> 5;
    const int xv = lrow & 7, yv = (lrow >> 3) & 3;
    const int arow0 = (2*wave + 1) * HXY + (yv + 1) * HX + (xv + 1);

    f32x16 acc00, acc01, acc10, acc11;
    #pragma unroll
    for (int i = 0; i < 16; ++i) { acc00[i]=0.f; acc01[i]=0.f; acc10[i]=0.f; acc11[i]=0.f; }

    __syncthreads();   // ridx + obuf visible

    // ---- prologue: DMA halo quarter p=0 into buf0 ----
    #pragma unroll
    for (int it = 0; it < 5; ++it) {
        int task = it * 256 + tid;
        if (task < NH * 2) {
            int r  = task >> 1;
            int hl = task & 1;
            int idx = ridx[r];
            const __bf16* src = (idx >= 0) ? featsB + (size_t)idx * 64 + hl * 8
                                           : zrow;
            GLD_LDS16(src, (char*)halo + task * 16);
        }
    }
    __syncthreads();   // vmcnt(0) drain -> buf0 ready

    #pragma unroll 1
    for (int p = 0; p < 4; ++p) {
        const __bf16* Ab0 = halo + (p & 1) * (NH * 16) + arow0 * 16 + halfk * 8;
        const __bf16* Bg0 = Wt4 + (size_t)p * 27648 + lrow * 16 + halfk * 8;

        // ---- B ring prologue: taps 0..3 (before the DMA: FIFO vmcnt) ----
        bf16x8 rb0[4], rb1[4];
        #pragma unroll
        for (int i = 0; i < 4; ++i) {
            rb0[i] = *(const bf16x8*)(Bg0 + i * 1024);
            rb1[i] = *(const bf16x8*)(Bg0 + i * 1024 + 512);
        }

        // ---- issue next pass's halo DMA into the other buffer ----
        if (p < 3) {
            char* dst = (char*)halo + ((p + 1) & 1) * (NH * 16 * 2);
            #pragma unroll
            for (int it = 0; it < 5; ++it) {
                int task = it * 256 + tid;
                if (task < NH * 2) {
                    int r  = task >> 1;
                    int hl = task & 1;
                    int idx = ridx[r];
                    const __bf16* src = (idx >= 0)
                        ? featsB + (size_t)idx * 64 + (p + 1) * 16 + hl * 8
                        : zrow;
                    GLD_LDS16(src, dst + task * 16);
                }
            }
        }

        // ---- 27 taps: A from LDS, B from the 4-deep ring ----
        #pragma unroll
        for (int t = 0; t < 27; ++t) {
            const int drow = (t/9 - 1)*HXY + ((t/3)%3 - 1)*HX + (t%3 - 1);
            bf16x8 a0 = *(const bf16x8*)(Ab0 + drow * 16);
            bf16x8 a1 = *(const bf16x8*)(Ab0 + (drow + HXY) * 16);
            bf16x8 b0 = rb0[t & 3];
            bf16x8 b1 = rb1[t & 3];
            if (t + 4 < 27) {   // refill the slot just consumed with tap t+4
                rb0[t & 3] = *(const bf16x8*)(Bg0 + (t + 4) * 1024);
                rb1[t & 3] = *(const bf16x8*)(Bg0 + (t + 4) * 1024 + 512);
            }
            acc00 = __builtin_amdgcn_mfma_f32_32x32x16_bf16(a0, b0, acc00, 0, 0, 0);
            acc01 = __builtin_amdgcn_mfma_f32_32x32x16_bf16(a0, b1, acc01, 0, 0, 0);
            acc10 = __builtin_amdgcn_mfma_f32_32x32x16_bf16(a1, b0, acc10, 0, 0, 0);
            acc11 = __builtin_amdgcn_mfma_f32_32x32x16_bf16(a1, b1, acc11, 0, 0, 0);
        }

        // one barrier: retires next-pass DMA + closes this buffer
        if (p < 3) __syncthreads();
    }

    // ---- epilogue: C/D layout col=lane&31, row=(reg&3)+8*(reg>>2)+4*(lane>>5) ----
    const int col0 = lrow, col1 = 32 + lrow;
    const float bv0 = bias[col0], bv1 = bias[col1];
    #pragma unroll
    for (int r = 0; r < 16; ++r) {
        int mrow = (r & 3) + 8 * (r >> 2) + 4 * halfk;
        int o0 = obuf[(2*wave)     * 32 + mrow];
        int o1 = obuf[(2*wave + 1) * 32 + mrow];
        if (o0 >= 0) {
            out[(size_t)o0 * 64 + col0] = acc00[r] + bv0;
            out[(size_t)o0 * 64 + col1] = acc01[r] + bv1;
        }
        if (o1 >= 0) {
            out[(size_t)o1 * 64 + col0] = acc10[r] + bv0;
            out[(size_t)o1 * 64 + col1] = acc11[r] + bv1;
        }
    }
}

extern "C" void kernel_launch(void* const* d_in, const int* in_sizes, int n_in,
                              void* d_out, int out_size, void* d_ws, size_t ws_size,
                              hipStream_t stream) {
    const float* feats = (const float*)d_in[0];
    const float* ipos  = (const float*)d_in[1];
    const float* opos  = (const float*)d_in[2];
    const float* vsp   = (const float*)d_in[3];
    const float* W     = (const float*)d_in[4];
    const float* bias  = (const float*)d_in[5];

    int N = in_sizes[0] / 64;
    int M = out_size / 64;

    // workspace: imap | omap | ikey | okey | Wt4 | zrow | featsB (~15.5 MB)
    int*    imap   = (int*)d_ws;
    int*    omap   = imap + NROWS;
    int*    ikey   = omap + NROWS;
    int*    okey   = ikey + N;
    __bf16* Wt4    = (__bf16*)(okey + M);
    __bf16* zrow   = Wt4 + K3CC;
    __bf16* featsB = zrow + 32;

    int total = N + M + K3CC + 32 + N * 8;
    prep_kernel<<<(total + 255) / 256, 256, 0, stream>>>(ipos, N, opos, M, vsp, W, feats,
                                                         imap, ikey, omap, okey,
                                                         Wt4, zrow, featsB);
    conv_kernel<<<8 * SLAB, 256, 0, stream>>>(featsB, Wt4, zrow, bias,
                                              imap, ikey, omap, okey,
                                              (float*)d_out, N, M);
}